// Round 1
// baseline (2825.032 us; speedup 1.0000x reference)
//
#include <hip/hip_runtime.h>

#define NN 100000
#define D  128
#define NE 1600000

// ---------------------------------------------------------------------------
// Kernel 1: agg = node_feature   (EPS = 0, so h = x + sum_neighbors)
// ---------------------------------------------------------------------------
__global__ void init_agg_kernel(const float* __restrict__ x, float* __restrict__ agg) {
    const int n4 = NN * D / 4;
    for (int i = blockIdx.x * blockDim.x + threadIdx.x; i < n4;
         i += gridDim.x * blockDim.x) {
        reinterpret_cast<float4*>(agg)[i] = reinterpret_cast<const float4*>(x)[i];
    }
}

// ---------------------------------------------------------------------------
// Kernel 2: scatter-add  agg[dst] += x[src]  — 32 lanes per edge, float4 each
// ---------------------------------------------------------------------------
__global__ void scatter_add_kernel(const float* __restrict__ x,
                                   const int* __restrict__ ei,
                                   float* __restrict__ agg) {
    long long gid = (long long)blockIdx.x * blockDim.x + threadIdx.x;
    int edge = (int)(gid >> 5);
    int lane = (int)(gid & 31);
    if (edge >= NE) return;
    int src = ei[edge];
    int dst = ei[NE + edge];
    if ((unsigned)src >= NN || (unsigned)dst >= NN) return;   // dtype-surprise guard
    float4 v = reinterpret_cast<const float4*>(x + (size_t)src * D)[lane];
    float* a = agg + (size_t)dst * D + lane * 4;
    atomicAdd(a + 0, v.x);
    atomicAdd(a + 1, v.y);
    atomicAdd(a + 2, v.z);
    atomicAdd(a + 3, v.w);
}

// ---------------------------------------------------------------------------
// Kernel 3: fused MLP   out = relu(h@W1 + b1) @ W2 + b2
// 64 rows per block, 512 threads, W staged in LDS (W1 then W2), h1 kept in LDS
// Each thread owns a 4x4 (row x col) register tile.
// ---------------------------------------------------------------------------
#define ROWS 64

__global__ __launch_bounds__(512)
void mlp_kernel(const float* __restrict__ agg,
                const float* __restrict__ W1, const float* __restrict__ b1,
                const float* __restrict__ W2, const float* __restrict__ b2,
                float* __restrict__ out) {
    __shared__ float sh_h[ROWS][D];   // 32 KB: h rows, then h1 rows
    __shared__ float sh_w[D][D];      // 64 KB: W1, then W2

    const int tid  = threadIdx.x;
    const int row0 = blockIdx.x * ROWS;

    // --- stage h tile (zero-pad past NN) and W1 ---
    {
        const float4* src = reinterpret_cast<const float4*>(agg + (size_t)row0 * D);
        float4* dstp = reinterpret_cast<float4*>(&sh_h[0][0]);
        const int total4 = ROWS * D / 4;                 // 2048
        for (int i = tid; i < total4; i += 512) {
            int r = i / (D / 4);
            dstp[i] = (row0 + r < NN) ? src[i] : make_float4(0.f, 0.f, 0.f, 0.f);
        }
        const float4* w1v = reinterpret_cast<const float4*>(W1);
        float4* wd = reinterpret_cast<float4*>(&sh_w[0][0]);
        for (int i = tid; i < D * D / 4; i += 512) wd[i] = w1v[i];
    }
    __syncthreads();

    const int tr = tid >> 5;          // 0..15
    const int tc = tid & 31;          // 0..31
    const int r0 = tr * 4;
    const int c0 = tc * 4;

    // --- GEMM1: acc = h @ W1 ---
    float acc[4][4] = {};
    for (int k = 0; k < D; ++k) {
        float a0 = sh_h[r0 + 0][k];
        float a1 = sh_h[r0 + 1][k];
        float a2 = sh_h[r0 + 2][k];
        float a3 = sh_h[r0 + 3][k];
        float4 b4 = *reinterpret_cast<const float4*>(&sh_w[k][c0]);
        acc[0][0] = fmaf(a0, b4.x, acc[0][0]); acc[0][1] = fmaf(a0, b4.y, acc[0][1]);
        acc[0][2] = fmaf(a0, b4.z, acc[0][2]); acc[0][3] = fmaf(a0, b4.w, acc[0][3]);
        acc[1][0] = fmaf(a1, b4.x, acc[1][0]); acc[1][1] = fmaf(a1, b4.y, acc[1][1]);
        acc[1][2] = fmaf(a1, b4.z, acc[1][2]); acc[1][3] = fmaf(a1, b4.w, acc[1][3]);
        acc[2][0] = fmaf(a2, b4.x, acc[2][0]); acc[2][1] = fmaf(a2, b4.y, acc[2][1]);
        acc[2][2] = fmaf(a2, b4.z, acc[2][2]); acc[2][3] = fmaf(a2, b4.w, acc[2][3]);
        acc[3][0] = fmaf(a3, b4.x, acc[3][0]); acc[3][1] = fmaf(a3, b4.y, acc[3][1]);
        acc[3][2] = fmaf(a3, b4.z, acc[3][2]); acc[3][3] = fmaf(a3, b4.w, acc[3][3]);
    }

    // --- bias + relu ---
    float bias1[4] = {b1[c0 + 0], b1[c0 + 1], b1[c0 + 2], b1[c0 + 3]};
    #pragma unroll
    for (int i = 0; i < 4; ++i)
        #pragma unroll
        for (int j = 0; j < 4; ++j)
            acc[i][j] = fmaxf(acc[i][j] + bias1[j], 0.f);

    __syncthreads();   // all reads of sh_h / sh_w done

    // --- write h1 into sh_h, stage W2 into sh_w ---
    #pragma unroll
    for (int i = 0; i < 4; ++i) {
        float4 v = make_float4(acc[i][0], acc[i][1], acc[i][2], acc[i][3]);
        *reinterpret_cast<float4*>(&sh_h[r0 + i][c0]) = v;
    }
    {
        const float4* w2v = reinterpret_cast<const float4*>(W2);
        float4* wd = reinterpret_cast<float4*>(&sh_w[0][0]);
        for (int i = tid; i < D * D / 4; i += 512) wd[i] = w2v[i];
    }
    __syncthreads();

    // --- GEMM2: acc2 = h1 @ W2 ---
    float acc2[4][4] = {};
    for (int k = 0; k < D; ++k) {
        float a0 = sh_h[r0 + 0][k];
        float a1 = sh_h[r0 + 1][k];
        float a2 = sh_h[r0 + 2][k];
        float a3 = sh_h[r0 + 3][k];
        float4 b4 = *reinterpret_cast<const float4*>(&sh_w[k][c0]);
        acc2[0][0] = fmaf(a0, b4.x, acc2[0][0]); acc2[0][1] = fmaf(a0, b4.y, acc2[0][1]);
        acc2[0][2] = fmaf(a0, b4.z, acc2[0][2]); acc2[0][3] = fmaf(a0, b4.w, acc2[0][3]);
        acc2[1][0] = fmaf(a1, b4.x, acc2[1][0]); acc2[1][1] = fmaf(a1, b4.y, acc2[1][1]);
        acc2[1][2] = fmaf(a1, b4.z, acc2[1][2]); acc2[1][3] = fmaf(a1, b4.w, acc2[1][3]);
        acc2[2][0] = fmaf(a2, b4.x, acc2[2][0]); acc2[2][1] = fmaf(a2, b4.y, acc2[2][1]);
        acc2[2][2] = fmaf(a2, b4.z, acc2[2][2]); acc2[2][3] = fmaf(a2, b4.w, acc2[2][3]);
        acc2[3][0] = fmaf(a3, b4.x, acc2[3][0]); acc2[3][1] = fmaf(a3, b4.y, acc2[3][1]);
        acc2[3][2] = fmaf(a3, b4.z, acc2[3][2]); acc2[3][3] = fmaf(a3, b4.w, acc2[3][3]);
    }

    // --- bias2 + store ---
    float bias2[4] = {b2[c0 + 0], b2[c0 + 1], b2[c0 + 2], b2[c0 + 3]};
    #pragma unroll
    for (int i = 0; i < 4; ++i) {
        int row = row0 + r0 + i;
        if (row < NN) {
            float4 v = make_float4(acc2[i][0] + bias2[0], acc2[i][1] + bias2[1],
                                   acc2[i][2] + bias2[2], acc2[i][3] + bias2[3]);
            *reinterpret_cast<float4*>(out + (size_t)row * D + c0) = v;
        }
    }
}

// ---------------------------------------------------------------------------
extern "C" void kernel_launch(void* const* d_in, const int* in_sizes, int n_in,
                              void* d_out, int out_size, void* d_ws, size_t ws_size,
                              hipStream_t stream) {
    const float* x  = (const float*)d_in[0];
    const int*   ei = (const int*)d_in[1];
    const float* W1 = (const float*)d_in[2];
    const float* b1 = (const float*)d_in[3];
    const float* W2 = (const float*)d_in[4];
    const float* b2 = (const float*)d_in[5];
    float* out = (float*)d_out;
    float* agg = (float*)d_ws;                       // NN*D*4 = 51.2 MB scratch

    // Phase 1a: agg = x
    init_agg_kernel<<<2048, 256, 0, stream>>>(x, agg);

    // Phase 1b: agg[dst] += x[src] for every edge
    {
        long long threads = (long long)NE * 32;
        int blocks = (int)((threads + 255) / 256);   // 200000
        scatter_add_kernel<<<blocks, 256, 0, stream>>>(x, ei, agg);
    }

    // Phase 2: out = relu(agg@W1+b1)@W2+b2
    {
        int blocks = (NN + ROWS - 1) / ROWS;         // 1563
        mlp_kernel<<<blocks, 512, 0, stream>>>(agg, W1, b1, W2, b2, out);
    }
}

// Round 2
// 443.004 us; speedup vs baseline: 6.3770x; 6.3770x over previous
//
#include <hip/hip_runtime.h>

#define NN 100000
#define D  128
#define NE 1600000
#define NB 196            // ceil(NN / 512) scan blocks

// ---------------------------------------------------------------------------
// CSR build: counts -> exclusive scan -> bucket fill (all in d_ws)
// ---------------------------------------------------------------------------
__global__ void zero_kernel(int* __restrict__ counts) {
    int i = blockIdx.x * blockDim.x + threadIdx.x;
    if (i < NN) counts[i] = 0;
}

__global__ void hist_kernel(const int* __restrict__ ei, int* __restrict__ counts) {
    int e = blockIdx.x * blockDim.x + threadIdx.x;
    if (e >= NE) return;
    int d = ei[NE + e];
    if ((unsigned)d < NN) atomicAdd(&counts[d], 1);
}

__global__ __launch_bounds__(512)
void scan_a_kernel(const int* __restrict__ counts, int* __restrict__ blockSums) {
    __shared__ int s[512];
    int t = threadIdx.x;
    int i = blockIdx.x * 512 + t;
    s[t] = (i < NN) ? counts[i] : 0;
    __syncthreads();
    for (int off = 256; off > 0; off >>= 1) {
        if (t < off) s[t] += s[t + off];
        __syncthreads();
    }
    if (t == 0) blockSums[blockIdx.x] = s[0];
}

__global__ __launch_bounds__(256)
void scan_b_kernel(int* __restrict__ blockSums, int* __restrict__ offsets) {
    __shared__ int s[256];
    int t = threadIdx.x;
    int v = (t < NB) ? blockSums[t] : 0;
    s[t] = v;
    __syncthreads();
    for (int off = 1; off < 256; off <<= 1) {
        int add = (t >= off) ? s[t - off] : 0;
        __syncthreads();
        s[t] += add;
        __syncthreads();
    }
    if (t < NB) blockSums[t] = s[t] - v;      // exclusive block prefix
    if (t == 255) offsets[NN] = s[255];       // total valid edges
}

__global__ __launch_bounds__(512)
void scan_c_kernel(const int* __restrict__ counts, const int* __restrict__ blockSums,
                   int* __restrict__ offsets, int* __restrict__ cursor) {
    __shared__ int s[512];
    int t = threadIdx.x;
    int i = blockIdx.x * 512 + t;
    int v = (i < NN) ? counts[i] : 0;
    s[t] = v;
    __syncthreads();
    for (int off = 1; off < 512; off <<= 1) {
        int add = (t >= off) ? s[t - off] : 0;
        __syncthreads();
        s[t] += add;
        __syncthreads();
    }
    int excl = s[t] - v + blockSums[blockIdx.x];
    if (i < NN) { offsets[i] = excl; cursor[i] = excl; }
}

__global__ void fill_kernel(const int* __restrict__ ei, int* __restrict__ cursor,
                            int* __restrict__ srclist) {
    int e = blockIdx.x * blockDim.x + threadIdx.x;
    if (e >= NE) return;
    int s = ei[e];
    int d = ei[NE + e];
    if ((unsigned)s >= NN || (unsigned)d >= NN) return;
    int pos = atomicAdd(&cursor[d], 1);
    srclist[pos] = s;
}

// ---------------------------------------------------------------------------
// Gather: h[n] = x[n] + sum_{s in nbrs(n)} x[s]   (32 lanes per node, float4)
// ---------------------------------------------------------------------------
__global__ void gather_kernel(const float* __restrict__ x,
                              const int* __restrict__ offsets,
                              const int* __restrict__ srclist,
                              float* __restrict__ h) {
    int gid  = blockIdx.x * blockDim.x + threadIdx.x;
    int node = gid >> 5;
    int lane = gid & 31;
    if (node >= NN) return;
    int beg = offsets[node];
    int end = offsets[node + 1];
    const float4* xv = reinterpret_cast<const float4*>(x);
    float4 acc = xv[(size_t)node * 32 + lane];
    for (int j = beg; j < end; ++j) {
        int s = srclist[j];
        float4 v = xv[(size_t)s * 32 + lane];
        acc.x += v.x; acc.y += v.y; acc.z += v.z; acc.w += v.w;
    }
    reinterpret_cast<float4*>(h)[(size_t)node * 32 + lane] = acc;
}

// ---------------------------------------------------------------------------
// Fused MLP: out = relu(h@W1 + b1) @ W2 + b2   (reads/writes d_out in place,
// each block touches only its own 64 rows)
// ---------------------------------------------------------------------------
#define ROWS 64

__global__ __launch_bounds__(512)
void mlp_kernel(const float* __restrict__ W1, const float* __restrict__ b1,
                const float* __restrict__ W2, const float* __restrict__ b2,
                float* __restrict__ hout) {
    __shared__ float sh_h[ROWS][D];   // 32 KB
    __shared__ float sh_w[D][D];      // 64 KB

    const int tid  = threadIdx.x;
    const int row0 = blockIdx.x * ROWS;

    {
        const float4* src = reinterpret_cast<const float4*>(hout + (size_t)row0 * D);
        float4* dstp = reinterpret_cast<float4*>(&sh_h[0][0]);
        const int total4 = ROWS * D / 4;
        for (int i = tid; i < total4; i += 512) {
            int r = i / (D / 4);
            dstp[i] = (row0 + r < NN) ? src[i] : make_float4(0.f, 0.f, 0.f, 0.f);
        }
        const float4* w1v = reinterpret_cast<const float4*>(W1);
        float4* wd = reinterpret_cast<float4*>(&sh_w[0][0]);
        for (int i = tid; i < D * D / 4; i += 512) wd[i] = w1v[i];
    }
    __syncthreads();

    const int tr = tid >> 5;
    const int tc = tid & 31;
    const int r0 = tr * 4;
    const int c0 = tc * 4;

    float acc[4][4] = {};
    for (int k = 0; k < D; ++k) {
        float a0 = sh_h[r0 + 0][k];
        float a1 = sh_h[r0 + 1][k];
        float a2 = sh_h[r0 + 2][k];
        float a3 = sh_h[r0 + 3][k];
        float4 b4 = *reinterpret_cast<const float4*>(&sh_w[k][c0]);
        acc[0][0] = fmaf(a0, b4.x, acc[0][0]); acc[0][1] = fmaf(a0, b4.y, acc[0][1]);
        acc[0][2] = fmaf(a0, b4.z, acc[0][2]); acc[0][3] = fmaf(a0, b4.w, acc[0][3]);
        acc[1][0] = fmaf(a1, b4.x, acc[1][0]); acc[1][1] = fmaf(a1, b4.y, acc[1][1]);
        acc[1][2] = fmaf(a1, b4.z, acc[1][2]); acc[1][3] = fmaf(a1, b4.w, acc[1][3]);
        acc[2][0] = fmaf(a2, b4.x, acc[2][0]); acc[2][1] = fmaf(a2, b4.y, acc[2][1]);
        acc[2][2] = fmaf(a2, b4.z, acc[2][2]); acc[2][3] = fmaf(a2, b4.w, acc[2][3]);
        acc[3][0] = fmaf(a3, b4.x, acc[3][0]); acc[3][1] = fmaf(a3, b4.y, acc[3][1]);
        acc[3][2] = fmaf(a3, b4.z, acc[3][2]); acc[3][3] = fmaf(a3, b4.w, acc[3][3]);
    }

    float bias1[4] = {b1[c0 + 0], b1[c0 + 1], b1[c0 + 2], b1[c0 + 3]};
    #pragma unroll
    for (int i = 0; i < 4; ++i)
        #pragma unroll
        for (int j = 0; j < 4; ++j)
            acc[i][j] = fmaxf(acc[i][j] + bias1[j], 0.f);

    __syncthreads();

    #pragma unroll
    for (int i = 0; i < 4; ++i) {
        float4 v = make_float4(acc[i][0], acc[i][1], acc[i][2], acc[i][3]);
        *reinterpret_cast<float4*>(&sh_h[r0 + i][c0]) = v;
    }
    {
        const float4* w2v = reinterpret_cast<const float4*>(W2);
        float4* wd = reinterpret_cast<float4*>(&sh_w[0][0]);
        for (int i = tid; i < D * D / 4; i += 512) wd[i] = w2v[i];
    }
    __syncthreads();

    float acc2[4][4] = {};
    for (int k = 0; k < D; ++k) {
        float a0 = sh_h[r0 + 0][k];
        float a1 = sh_h[r0 + 1][k];
        float a2 = sh_h[r0 + 2][k];
        float a3 = sh_h[r0 + 3][k];
        float4 b4 = *reinterpret_cast<const float4*>(&sh_w[k][c0]);
        acc2[0][0] = fmaf(a0, b4.x, acc2[0][0]); acc2[0][1] = fmaf(a0, b4.y, acc2[0][1]);
        acc2[0][2] = fmaf(a0, b4.z, acc2[0][2]); acc2[0][3] = fmaf(a0, b4.w, acc2[0][3]);
        acc2[1][0] = fmaf(a1, b4.x, acc2[1][0]); acc2[1][1] = fmaf(a1, b4.y, acc2[1][1]);
        acc2[1][2] = fmaf(a1, b4.z, acc2[1][2]); acc2[1][3] = fmaf(a1, b4.w, acc2[1][3]);
        acc2[2][0] = fmaf(a2, b4.x, acc2[2][0]); acc2[2][1] = fmaf(a2, b4.y, acc2[2][1]);
        acc2[2][2] = fmaf(a2, b4.z, acc2[2][2]); acc2[2][3] = fmaf(a2, b4.w, acc2[2][3]);
        acc2[3][0] = fmaf(a3, b4.x, acc2[3][0]); acc2[3][1] = fmaf(a3, b4.y, acc2[3][1]);
        acc2[3][2] = fmaf(a3, b4.z, acc2[3][2]); acc2[3][3] = fmaf(a3, b4.w, acc2[3][3]);
    }

    float bias2[4] = {b2[c0 + 0], b2[c0 + 1], b2[c0 + 2], b2[c0 + 3]};
    #pragma unroll
    for (int i = 0; i < 4; ++i) {
        int row = row0 + r0 + i;
        if (row < NN) {
            float4 v = make_float4(acc2[i][0] + bias2[0], acc2[i][1] + bias2[1],
                                   acc2[i][2] + bias2[2], acc2[i][3] + bias2[3]);
            *reinterpret_cast<float4*>(hout + (size_t)row * D + c0) = v;
        }
    }
}

// ---------------------------------------------------------------------------
extern "C" void kernel_launch(void* const* d_in, const int* in_sizes, int n_in,
                              void* d_out, int out_size, void* d_ws, size_t ws_size,
                              hipStream_t stream) {
    const float* x  = (const float*)d_in[0];
    const int*   ei = (const int*)d_in[1];
    const float* W1 = (const float*)d_in[2];
    const float* b1 = (const float*)d_in[3];
    const float* W2 = (const float*)d_in[4];
    const float* b2 = (const float*)d_in[5];
    float* out = (float*)d_out;

    // workspace layout (ints): counts | offsets | cursor | blockSums | srclist
    int* counts    = (int*)d_ws;
    int* offsets   = counts + NN;
    int* cursor    = offsets + NN + 1;
    int* blockSums = cursor + NN;
    int* srclist   = blockSums + 256;

    zero_kernel<<<(NN + 255) / 256, 256, 0, stream>>>(counts);
    hist_kernel<<<(NE + 255) / 256, 256, 0, stream>>>(ei, counts);
    scan_a_kernel<<<NB, 512, 0, stream>>>(counts, blockSums);
    scan_b_kernel<<<1, 256, 0, stream>>>(blockSums, offsets);
    scan_c_kernel<<<NB, 512, 0, stream>>>(counts, blockSums, offsets, cursor);
    fill_kernel<<<(NE + 255) / 256, 256, 0, stream>>>(ei, cursor, srclist);

    // h = x + gather  (written into d_out)
    {
        long long threads = (long long)NN * 32;
        int blocks = (int)((threads + 255) / 256);     // 12500
        gather_kernel<<<blocks, 256, 0, stream>>>(x, offsets, srclist, out);
    }

    // out = relu(h@W1+b1)@W2+b2  (in place on d_out)
    mlp_kernel<<<(NN + ROWS - 1) / ROWS, 512, 0, stream>>>(W1, b1, W2, b2, out);
}

// Round 3
// 305.965 us; speedup vs baseline: 9.2332x; 1.4479x over previous
//
#include <hip/hip_runtime.h>

#define NN 100000
#define D  128
#define NE 1600000
#define NB 196            // ceil(NN / 512) scan blocks

typedef __bf16 bf16x8 __attribute__((ext_vector_type(8)));
typedef __bf16 bf16x4 __attribute__((ext_vector_type(4)));
typedef float  f32x4  __attribute__((ext_vector_type(4)));

// ---------------------------------------------------------------------------
// Prep: xb = bf16(x)   [NN][128]
// ---------------------------------------------------------------------------
__global__ void xprep_kernel(const float* __restrict__ x, __bf16* __restrict__ xb) {
    int i = blockIdx.x * 256 + threadIdx.x;          // over NN*32 float4 chunks
    if (i < NN * 32) {
        float4 v = reinterpret_cast<const float4*>(x)[i];
        bf16x4 o = {(__bf16)v.x, (__bf16)v.y, (__bf16)v.z, (__bf16)v.w};
        reinterpret_cast<bf16x4*>(xb)[i] = o;
    }
}

// Prep: w1t[c][k] = bf16(W1[k][c]), w2t likewise (transposed for B-fragments)
__global__ void wprep_kernel(const float* __restrict__ W1, const float* __restrict__ W2,
                             __bf16* __restrict__ w1t, __bf16* __restrict__ w2t) {
    int i = blockIdx.x * 256 + threadIdx.x;
    if (i < 16384) {
        int c = i >> 7, k = i & 127;
        w1t[i] = (__bf16)W1[k * 128 + c];
    } else if (i < 32768) {
        int j = i - 16384;
        int c = j >> 7, k = j & 127;
        w2t[j] = (__bf16)W2[k * 128 + c];
    }
}

// ---------------------------------------------------------------------------
// CSR build: counts -> exclusive scan -> bucket fill (all in d_ws)
// ---------------------------------------------------------------------------
__global__ void zero_kernel(int* __restrict__ counts) {
    int i = blockIdx.x * blockDim.x + threadIdx.x;
    if (i < NN) counts[i] = 0;
}

__global__ void hist_kernel(const int* __restrict__ ei, int* __restrict__ counts) {
    int e = blockIdx.x * blockDim.x + threadIdx.x;
    if (e >= NE) return;
    int d = ei[NE + e];
    if ((unsigned)d < NN) atomicAdd(&counts[d], 1);
}

__global__ __launch_bounds__(512)
void scan_a_kernel(const int* __restrict__ counts, int* __restrict__ blockSums) {
    __shared__ int s[512];
    int t = threadIdx.x;
    int i = blockIdx.x * 512 + t;
    s[t] = (i < NN) ? counts[i] : 0;
    __syncthreads();
    for (int off = 256; off > 0; off >>= 1) {
        if (t < off) s[t] += s[t + off];
        __syncthreads();
    }
    if (t == 0) blockSums[blockIdx.x] = s[0];
}

__global__ __launch_bounds__(256)
void scan_b_kernel(int* __restrict__ blockSums, int* __restrict__ offsets) {
    __shared__ int s[256];
    int t = threadIdx.x;
    int v = (t < NB) ? blockSums[t] : 0;
    s[t] = v;
    __syncthreads();
    for (int off = 1; off < 256; off <<= 1) {
        int add = (t >= off) ? s[t - off] : 0;
        __syncthreads();
        s[t] += add;
        __syncthreads();
    }
    if (t < NB) blockSums[t] = s[t] - v;      // exclusive block prefix
    if (t == 255) offsets[NN] = s[255];       // total valid edges
}

__global__ __launch_bounds__(512)
void scan_c_kernel(const int* __restrict__ counts, const int* __restrict__ blockSums,
                   int* __restrict__ offsets, int* __restrict__ cursor) {
    __shared__ int s[512];
    int t = threadIdx.x;
    int i = blockIdx.x * 512 + t;
    int v = (i < NN) ? counts[i] : 0;
    s[t] = v;
    __syncthreads();
    for (int off = 1; off < 512; off <<= 1) {
        int add = (t >= off) ? s[t - off] : 0;
        __syncthreads();
        s[t] += add;
        __syncthreads();
    }
    int excl = s[t] - v + blockSums[blockIdx.x];
    if (i < NN) { offsets[i] = excl; cursor[i] = excl; }
}

__global__ void fill_kernel(const int* __restrict__ ei, int* __restrict__ cursor,
                            int* __restrict__ srclist) {
    int e = blockIdx.x * blockDim.x + threadIdx.x;
    if (e >= NE) return;
    int s = ei[e];
    int d = ei[NE + e];
    if ((unsigned)s >= NN || (unsigned)d >= NN) return;
    int pos = atomicAdd(&cursor[d], 1);
    srclist[pos] = s;
}

// ---------------------------------------------------------------------------
// Gather: hb[n] = bf16( x[n] + sum_{s in nbrs(n)} x[s] )  — 32 lanes/node
// ---------------------------------------------------------------------------
__global__ void gather_kernel(const __bf16* __restrict__ xb,
                              const int* __restrict__ offsets,
                              const int* __restrict__ srclist,
                              __bf16* __restrict__ hb) {
    int gid  = blockIdx.x * blockDim.x + threadIdx.x;
    int node = gid >> 5;
    int lane = gid & 31;
    if (node >= NN) return;
    int beg = offsets[node];
    int end = offsets[node + 1];
    const bf16x4* xv = reinterpret_cast<const bf16x4*>(xb);
    bf16x4 self = xv[(size_t)node * 32 + lane];
    float a0 = (float)self[0], a1 = (float)self[1],
          a2 = (float)self[2], a3 = (float)self[3];
    for (int j0 = beg; j0 < end; j0 += 32) {
        int idx = j0 + lane;
        int s_reg = (idx < end) ? srclist[idx] : 0;
        int cnt = end - j0; if (cnt > 32) cnt = 32;
        for (int j = 0; j < cnt; ++j) {
            int s = __shfl(s_reg, j, 32);
            bf16x4 v = xv[(size_t)s * 32 + lane];
            a0 += (float)v[0]; a1 += (float)v[1];
            a2 += (float)v[2]; a3 += (float)v[3];
        }
    }
    bf16x4 o = {(__bf16)a0, (__bf16)a1, (__bf16)a2, (__bf16)a3};
    reinterpret_cast<bf16x4*>(hb)[(size_t)node * 32 + lane] = o;
}

// ---------------------------------------------------------------------------
// Fused MFMA MLP: out = relu(h@W1+b1)@W2+b2
// 256 thr / 4 waves, 64 rows per block. h + W^T staged in LDS (bf16, XOR-swz).
// Wave w owns output cols [32w, 32w+32): B-frags in regs, reused over 4 M-tiles.
// ---------------------------------------------------------------------------
__global__ __launch_bounds__(256)
void mlp_mfma_kernel(const __bf16* __restrict__ hb,
                     const __bf16* __restrict__ w1t,
                     const __bf16* __restrict__ w2t,
                     const float* __restrict__ b1,
                     const float* __restrict__ b2,
                     float* __restrict__ out) {
    __shared__ __align__(16) unsigned char sh_h[64 * 256];    // 16 KB
    __shared__ __align__(16) unsigned char sh_w[128 * 256];   // 32 KB

    const int tid   = threadIdx.x;
    const int wv    = tid >> 6;
    const int lane  = tid & 63;
    const int l15   = lane & 15;
    const int kbyte = (lane >> 4) * 16;      // byte offset of this lane's k-block
    const int row0  = blockIdx.x * 64;

    // stage h tile (swizzled)
    for (int c = tid; c < 1024; c += 256) {
        int r = c >> 4, s = c & 15;
        int grow = row0 + r;
        int4 val = make_int4(0, 0, 0, 0);
        if (grow < NN) val = *reinterpret_cast<const int4*>(hb + (size_t)grow * 128 + s * 8);
        *reinterpret_cast<int4*>(sh_h + r * 256 + ((s * 16) ^ ((r & 7) << 4))) = val;
    }
    // stage W1T (swizzled)
    for (int c = tid; c < 2048; c += 256) {
        int r = c >> 4, s = c & 15;
        int4 val = *reinterpret_cast<const int4*>(w1t + r * 128 + s * 8);
        *reinterpret_cast<int4*>(sh_w + r * 256 + ((s * 16) ^ ((r & 7) << 4))) = val;
    }
    __syncthreads();

    // ---- GEMM1 ----
    bf16x8 bf1[2][4];
    #pragma unroll
    for (int nn = 0; nn < 2; ++nn) {
        int col = wv * 32 + nn * 16 + l15;
        #pragma unroll
        for (int ks = 0; ks < 4; ++ks)
            bf1[nn][ks] = *reinterpret_cast<const bf16x8*>(
                sh_w + col * 256 + ((ks * 64 + kbyte) ^ ((col & 7) << 4)));
    }

    f32x4 acc[4][2];
    #pragma unroll
    for (int m = 0; m < 4; ++m) {
        acc[m][0] = f32x4{0.f, 0.f, 0.f, 0.f};
        acc[m][1] = f32x4{0.f, 0.f, 0.f, 0.f};
        int row = m * 16 + l15;
        bf16x8 af[4];
        #pragma unroll
        for (int ks = 0; ks < 4; ++ks)
            af[ks] = *reinterpret_cast<const bf16x8*>(
                sh_h + row * 256 + ((ks * 64 + kbyte) ^ ((row & 7) << 4)));
        #pragma unroll
        for (int ks = 0; ks < 4; ++ks) {
            acc[m][0] = __builtin_amdgcn_mfma_f32_16x16x32_bf16(af[ks], bf1[0][ks], acc[m][0], 0, 0, 0);
            acc[m][1] = __builtin_amdgcn_mfma_f32_16x16x32_bf16(af[ks], bf1[1][ks], acc[m][1], 0, 0, 0);
        }
    }

    float bias1a = b1[wv * 32 + l15];
    float bias1b = b1[wv * 32 + 16 + l15];

    __syncthreads();   // all GEMM1 LDS reads complete

    // h1 -> sh_h (bf16, swizzled)
    #pragma unroll
    for (int m = 0; m < 4; ++m) {
        #pragma unroll
        for (int nn = 0; nn < 2; ++nn) {
            int col = wv * 32 + nn * 16 + l15;
            float bb = nn ? bias1b : bias1a;
            #pragma unroll
            for (int j = 0; j < 4; ++j) {
                int row = m * 16 + (lane >> 4) * 4 + j;
                float v = fmaxf(acc[m][nn][j] + bb, 0.f);
                *reinterpret_cast<__bf16*>(
                    sh_h + row * 256 + ((col * 2) ^ ((row & 7) << 4))) = (__bf16)v;
            }
        }
    }
    // stage W2T (swizzled)
    for (int c = tid; c < 2048; c += 256) {
        int r = c >> 4, s = c & 15;
        int4 val = *reinterpret_cast<const int4*>(w2t + r * 128 + s * 8);
        *reinterpret_cast<int4*>(sh_w + r * 256 + ((s * 16) ^ ((r & 7) << 4))) = val;
    }
    __syncthreads();

    // ---- GEMM2 ----
    bf16x8 bf2[2][4];
    #pragma unroll
    for (int nn = 0; nn < 2; ++nn) {
        int col = wv * 32 + nn * 16 + l15;
        #pragma unroll
        for (int ks = 0; ks < 4; ++ks)
            bf2[nn][ks] = *reinterpret_cast<const bf16x8*>(
                sh_w + col * 256 + ((ks * 64 + kbyte) ^ ((col & 7) << 4)));
    }

    f32x4 acc2[4][2];
    #pragma unroll
    for (int m = 0; m < 4; ++m) {
        acc2[m][0] = f32x4{0.f, 0.f, 0.f, 0.f};
        acc2[m][1] = f32x4{0.f, 0.f, 0.f, 0.f};
        int row = m * 16 + l15;
        bf16x8 af[4];
        #pragma unroll
        for (int ks = 0; ks < 4; ++ks)
            af[ks] = *reinterpret_cast<const bf16x8*>(
                sh_h + row * 256 + ((ks * 64 + kbyte) ^ ((row & 7) << 4)));
        #pragma unroll
        for (int ks = 0; ks < 4; ++ks) {
            acc2[m][0] = __builtin_amdgcn_mfma_f32_16x16x32_bf16(af[ks], bf2[0][ks], acc2[m][0], 0, 0, 0);
            acc2[m][1] = __builtin_amdgcn_mfma_f32_16x16x32_bf16(af[ks], bf2[1][ks], acc2[m][1], 0, 0, 0);
        }
    }

    float bias2a = b2[wv * 32 + l15];
    float bias2b = b2[wv * 32 + 16 + l15];
    #pragma unroll
    for (int m = 0; m < 4; ++m) {
        #pragma unroll
        for (int nn = 0; nn < 2; ++nn) {
            int col = wv * 32 + nn * 16 + l15;
            float bb = nn ? bias2b : bias2a;
            #pragma unroll
            for (int j = 0; j < 4; ++j) {
                int row = row0 + m * 16 + (lane >> 4) * 4 + j;
                if (row < NN) out[(size_t)row * 128 + col] = acc2[m][nn][j] + bb;
            }
        }
    }
}

// ---------------------------------------------------------------------------
extern "C" void kernel_launch(void* const* d_in, const int* in_sizes, int n_in,
                              void* d_out, int out_size, void* d_ws, size_t ws_size,
                              hipStream_t stream) {
    const float* x  = (const float*)d_in[0];
    const int*   ei = (const int*)d_in[1];
    const float* W1 = (const float*)d_in[2];
    const float* b1 = (const float*)d_in[3];
    const float* W2 = (const float*)d_in[4];
    const float* b2 = (const float*)d_in[5];
    float* out = (float*)d_out;

    // ws layout: ints [counts|offsets|cursor|blockSums|srclist], then bf16 [xb|hb|w1t|w2t]
    int* counts    = (int*)d_ws;
    int* offsets   = counts + NN;
    int* cursor    = offsets + NN + 1;
    int* blockSums = cursor + NN;
    int* srclist   = blockSums + 256;
    size_t int_end = (size_t)(srclist + NE - counts) * 4;
    size_t bf_off  = (int_end + 255) & ~(size_t)255;
    __bf16* xb  = (__bf16*)((char*)d_ws + bf_off);
    __bf16* hb  = xb + (size_t)NN * D;
    __bf16* w1t = hb + (size_t)NN * D;
    __bf16* w2t = w1t + D * D;

    xprep_kernel<<<(NN * 32 + 255) / 256, 256, 0, stream>>>(x, xb);
    wprep_kernel<<<128, 256, 0, stream>>>(W1, W2, w1t, w2t);

    zero_kernel<<<(NN + 255) / 256, 256, 0, stream>>>(counts);
    hist_kernel<<<(NE + 255) / 256, 256, 0, stream>>>(ei, counts);
    scan_a_kernel<<<NB, 512, 0, stream>>>(counts, blockSums);
    scan_b_kernel<<<1, 256, 0, stream>>>(blockSums, offsets);
    scan_c_kernel<<<NB, 512, 0, stream>>>(counts, blockSums, offsets, cursor);
    fill_kernel<<<(NE + 255) / 256, 256, 0, stream>>>(ei, cursor, srclist);

    {
        long long threads = (long long)NN * 32;
        int blocks = (int)((threads + 255) / 256);     // 12500
        gather_kernel<<<blocks, 256, 0, stream>>>(xb, offsets, srclist, hb);
    }

    mlp_mfma_kernel<<<(NN + 63) / 64, 256, 0, stream>>>(hb, w1t, w2t, b1, b2, out);
}